// Round 8
// baseline (157.621 us; speedup 1.0000x reference)
//
#include <hip/hip_runtime.h>
#include <hip/hip_bf16.h>

// GLA forward, B=4 L=2048 D=1024 H=16 DK=DV=64.
// Round 8: pipelined GEMM — 3-LDS-buffer ring, depth-2 prefetch, counted
// s_waitcnt vmcnt(6) at tile boundaries (vmcnt(0) only once near the end),
// raw s_barrier + sched_barrier pins. Geometry unchanged from verified
// round 7 (256x128, BK=64, 8 waves 4Mx2N, XOR-swizzled LDS).
// Projection outputs now bf16 interleaved [8192][3072] (q|f logits|v);
// rowsoft reads/writes bf16 in place.

typedef __attribute__((ext_vector_type(8))) short s16x8;
typedef __attribute__((ext_vector_type(4))) float f32x4;

#define WIN 5
static const size_t NE = (size_t)8192 * 1024;

__device__ inline void gload16(const void* g, void* lds) {
  __builtin_amdgcn_global_load_lds(
      (const __attribute__((address_space(1))) unsigned int*)g,
      (__attribute__((address_space(3))) unsigned int*)lds, 16, 0, 0);
}

// ---------- 256x128 tile, BK=64, 8 waves (4M x 2N), 3-buffer ring ----------
// Swizzle (verified r6/r7): physical byte-in-row = logical ^ ((row&7)<<4),
// applied on the global SRC for staging (linear LDS dest) and on ds_read.
// EPI 1: store bf16 to Obf[row*3072 + col] (QFV interleaved).
// EPI 0: store f32 to C[row*1024 + col] (out projection).
template <int EPI>
__global__ __launch_bounds__(512, 2) void gemm_pipe(
    const __hip_bfloat16* __restrict__ A, const __hip_bfloat16* __restrict__ Bt,
    float* __restrict__ C, __hip_bfloat16* __restrict__ Obf, int K) {
  __shared__ __hip_bfloat16 sa[3][256 * 64];  // 96 KiB
  __shared__ __hip_bfloat16 sb[3][128 * 64];  // 48 KiB
  const int tid = threadIdx.x;
  const int lane = tid & 63;
  const int w = tid >> 6;
  const int wm = w >> 1, wn = w & 1;
  const int bm = blockIdx.y * 256, bn = blockIdx.x * 128;

  const int srow = tid >> 3;                      // staging row within 64-row round
  const int scol = ((tid & 7) ^ (srow & 7)) * 8;  // pre-swizzled global col
  const int r15 = lane & 15, g = lane >> 4;
  const int rx = (r15 & 7) << 4;                  // read-side XOR (bytes)

  const int NT = K / 64;  // 16
  // prologue: stage tiles 0 (buf0) and 1 (buf1); 6 calls/thread each
#pragma unroll
  for (int t0 = 0; t0 < 2; ++t0) {
#pragma unroll
    for (int r = 0; r < 4; ++r)
      gload16(A + (size_t)(bm + r * 64 + srow) * K + t0 * 64 + scol,
              &sa[t0][r * 4096 + tid * 8]);
#pragma unroll
    for (int r = 0; r < 2; ++r)
      gload16(Bt + (size_t)(bn + r * 64 + srow) * K + t0 * 64 + scol,
              &sb[t0][r * 4096 + tid * 8]);
  }
  asm volatile("s_waitcnt vmcnt(6)" ::: "memory");  // tile 0 landed; tile 1 in flight
  __builtin_amdgcn_s_barrier();
  __builtin_amdgcn_sched_barrier(0);

  __hip_bfloat16 *a_cur = sa[0], *a_nxt = sa[1], *a_st = sa[2];
  __hip_bfloat16 *b_cur = sb[0], *b_nxt = sb[1], *b_st = sb[2];

  f32x4 acc[4][4] = {};
  for (int t = 0; t < NT; ++t) {
    const int bk2 = (t + 2) * 64;
    // B fragments for the whole tile
    s16x8 bfr[4][2];
#pragma unroll
    for (int n = 0; n < 4; ++n)
#pragma unroll
      for (int ks = 0; ks < 2; ++ks)
        bfr[n][ks] = *(const s16x8*)((const char*)b_cur + (wn * 64 + n * 16 + r15) * 128 +
                                     ((g * 16 + ks * 64) ^ rx));
    // issue tile t+2 A-loads into a_st (buffer (t+2)%3: its last reader was
    // group t-1, which finished at the previous lgkmcnt(0)+barrier)
    if (t + 2 < NT) {
#pragma unroll
      for (int r = 0; r < 4; ++r)
        gload16(A + (size_t)(bm + r * 64 + srow) * K + bk2 + scol,
                a_st + r * 4096 + tid * 8);
    }
#pragma unroll
    for (int p = 0; p < 2; ++p) {
      s16x8 af[2][2];
#pragma unroll
      for (int mm = 0; mm < 2; ++mm)
#pragma unroll
        for (int ks = 0; ks < 2; ++ks)
          af[mm][ks] = *(const s16x8*)((const char*)a_cur +
                                       (wm * 64 + (p * 2 + mm) * 16 + r15) * 128 +
                                       ((g * 16 + ks * 64) ^ rx));
      if (p == 0 && t + 2 < NT) {
#pragma unroll
        for (int r = 0; r < 2; ++r)
          gload16(Bt + (size_t)(bn + r * 64 + srow) * K + bk2 + scol,
                  b_st + r * 4096 + tid * 8);
      }
      __builtin_amdgcn_s_setprio(1);
#pragma unroll
      for (int mm = 0; mm < 2; ++mm)
#pragma unroll
        for (int n = 0; n < 4; ++n)
#pragma unroll
          for (int ks = 0; ks < 2; ++ks)
            acc[p * 2 + mm][n] = __builtin_amdgcn_mfma_f32_16x16x32_bf16(
                af[mm][ks], bfr[n][ks], acc[p * 2 + mm][n], 0, 0, 0);
      __builtin_amdgcn_s_setprio(0);
      __builtin_amdgcn_sched_barrier(0);
    }
    // tile boundary: tile t+1 must be landed (6 newer calls of t+2 may fly)
    if (t + 1 < NT) {
      if (t + 2 < NT)
        asm volatile("s_waitcnt vmcnt(6) lgkmcnt(0)" ::: "memory");
      else
        asm volatile("s_waitcnt vmcnt(0) lgkmcnt(0)" ::: "memory");
      __builtin_amdgcn_s_barrier();
      __builtin_amdgcn_sched_barrier(0);
    }
    // rotate ring
    __hip_bfloat16* ta = a_cur; a_cur = a_nxt; a_nxt = a_st; a_st = ta;
    __hip_bfloat16* tb = b_cur; b_cur = b_nxt; b_nxt = b_st; b_st = tb;
  }

  // epilogue. C/D: col = lane&15, row = (lane>>4)*4 + reg
  const int rbase = bm + wm * 64 + (lane >> 4) * 4;
#pragma unroll
  for (int m = 0; m < 4; ++m)
#pragma unroll
    for (int n = 0; n < 4; ++n) {
      const int col = bn + wn * 64 + n * 16 + r15;
#pragma unroll
      for (int r = 0; r < 4; ++r) {
        if (EPI)
          Obf[(size_t)(rbase + m * 16 + r) * 3072 + col] = __float2bfloat16(acc[m][n][r]);
        else
          C[(size_t)(rbase + m * 16 + r) * 1024 + col] = acc[m][n][r];
      }
    }
}

__global__ __launch_bounds__(256) void cvt_bf16(const float* __restrict__ in,
                                                __hip_bfloat16* __restrict__ out) {
  const size_t i = ((size_t)blockIdx.x * 256 + threadIdx.x) * 4;
  float4 v = *reinterpret_cast<const float4*>(in + i);
  __hip_bfloat16 o4[4] = {__float2bfloat16(v.x), __float2bfloat16(v.y),
                          __float2bfloat16(v.z), __float2bfloat16(v.w)};
  *reinterpret_cast<uint2*>(out + i) = *reinterpret_cast<uint2*>(o4);
}

// Wt[z][n][k] = bf16(W_z[k][n]); z = blockIdx.z selects Wq/Wf/Wi/Wo.
__global__ __launch_bounds__(256) void cvt_transpose4(const float* __restrict__ Wq,
                                                      const float* __restrict__ Wf,
                                                      const float* __restrict__ Wi,
                                                      const float* __restrict__ Wo,
                                                      __hip_bfloat16* __restrict__ Wall) {
  const int z = blockIdx.z;
  const float* W = z == 0 ? Wq : z == 1 ? Wf : z == 2 ? Wi : Wo;
  __hip_bfloat16* Wt = Wall + (size_t)z * 1024 * 1024;
  __shared__ __hip_bfloat16 t[32][33];
  const int bx = blockIdx.x * 32, by = blockIdx.y * 32;
  const int tx = threadIdx.x & 31, ty = threadIdx.x >> 5;
#pragma unroll
  for (int i = 0; i < 4; ++i)
    t[ty + 8 * i][tx] = __float2bfloat16(W[(size_t)(by + ty + 8 * i) * 1024 + bx + tx]);
  __syncthreads();
#pragma unroll
  for (int i = 0; i < 4; ++i)
    Wt[(size_t)(bx + ty + 8 * i) * 1024 + by + tx] = t[tx][ty + 8 * i];
}

// In-place bf16 row softmax over the interleaved buffer.
// r < 8192: q slice (cols 0..1023), scaled by 0.125. r >= 8192: f slice
// (cols 1024..2047) -> e = softmax(f).
__global__ __launch_bounds__(256) void rowsoft2(__hip_bfloat16* __restrict__ qfv) {
  const int r = blockIdx.x;
  const int isF = r >> 13;
  const int row = r & 8191;
  __hip_bfloat16* p = qfv + (size_t)row * 3072 + (isF << 10);
  const int tid = threadIdx.x;
  ushort4 u = reinterpret_cast<ushort4*>(p)[tid];
  float4 v = make_float4(__uint_as_float((unsigned)u.x << 16),
                         __uint_as_float((unsigned)u.y << 16),
                         __uint_as_float((unsigned)u.z << 16),
                         __uint_as_float((unsigned)u.w << 16));
  float m = fmaxf(fmaxf(v.x, v.y), fmaxf(v.z, v.w));
#pragma unroll
  for (int off = 32; off; off >>= 1) m = fmaxf(m, __shfl_xor(m, off));
  __shared__ float redm[4];
  __shared__ float reds[4];
  if ((tid & 63) == 0) redm[tid >> 6] = m;
  __syncthreads();
  m = fmaxf(fmaxf(redm[0], redm[1]), fmaxf(redm[2], redm[3]));
  float e0 = expf(v.x - m), e1 = expf(v.y - m), e2 = expf(v.z - m), e3 = expf(v.w - m);
  float s = e0 + e1 + e2 + e3;
#pragma unroll
  for (int off = 32; off; off >>= 1) s += __shfl_xor(s, off);
  if ((tid & 63) == 0) reds[tid >> 6] = s;
  __syncthreads();
  s = reds[0] + reds[1] + reds[2] + reds[3];
  const float inv = (isF ? 1.0f : 0.125f) / s;
  __hip_bfloat16 o4[4] = {__float2bfloat16(e0 * inv), __float2bfloat16(e1 * inv),
                          __float2bfloat16(e2 * inv), __float2bfloat16(e3 * inv)};
  reinterpret_cast<ushort4*>(p)[tid] = *reinterpret_cast<ushort4*>(o4);
}

__device__ inline float wave_sum64(float x) {
  x += __int_as_float(__builtin_amdgcn_update_dpp(0, __float_as_int(x), 0xB1, 0xf, 0xf, true));
  x += __int_as_float(__builtin_amdgcn_update_dpp(0, __float_as_int(x), 0x4E, 0xf, 0xf, true));
  x += __int_as_float(__builtin_amdgcn_update_dpp(0, __float_as_int(x), 0x141, 0xf, 0xf, true));
  x += __int_as_float(__builtin_amdgcn_update_dpp(0, __float_as_int(x), 0x140, 0xf, 0xf, true));
  x += __int_as_float(__builtin_amdgcn_update_dpp(0, __float_as_int(x), 0x142, 0xa, 0xf, false));
  x += __int_as_float(__builtin_amdgcn_update_dpp(0, __float_as_int(x), 0x143, 0xc, 0xf, false));
  return __int_as_float(__builtin_amdgcn_readlane(__float_as_int(x), 63));
}

// Windowed GLA recurrence over bf16 interleaved [row][ q(1024) e(1024) v(1024) ].
// q pre-scaled by 0.125. One wave per (b,t,h).
__global__ __launch_bounds__(256) void gla_recur(const __hip_bfloat16* __restrict__ qfv,
                                                 __hip_bfloat16* __restrict__ o) {
  const int w = blockIdx.x * 4 + (threadIdx.x >> 6);
  const int lane = threadIdx.x & 63;
  const int h = w & 15;
  const int t = (w >> 4) & 2047;
  const int bL = w >> 15;
  const int row = (bL << 11) + t;
  const int col = (h << 6) + lane;
  const size_t rb = (size_t)row * 3072 + col;
  const float qv = __bfloat162float(qfv[rb]);
  const __hip_bfloat16* Ep = qfv + rb + 1024;
  const __hip_bfloat16* Vp = qfv + rb + 2048;
  float acc = 0.0f;
  if (t >= WIN) {
    float e[WIN + 1], pr[WIN + 1], vv[WIN + 1];
#pragma unroll
    for (int j = 0; j <= WIN; ++j) {
      e[j] = __bfloat162float(Ep[-j * 3072]);
      vv[j] = __bfloat162float(Vp[-j * 3072]);
    }
    float d = 1.0f;
#pragma unroll
    for (int j = 0; j <= WIN; ++j) {
      pr[j] = qv * d * (1.0f - e[j]);
      d *= e[j];
    }
#pragma unroll
    for (int j = 0; j <= WIN; ++j) pr[j] = wave_sum64(pr[j]);
#pragma unroll
    for (int j = 0; j <= WIN; ++j) acc = fmaf(pr[j], vv[j], acc);
  } else {
    float d = 1.0f;
    for (int j = 0; j <= t; ++j) {
      const float e = __bfloat162float(Ep[-j * 3072]);
      float pr = wave_sum64(qv * d * (1.0f - e));
      acc = fmaf(pr, __bfloat162float(Vp[-j * 3072]), acc);
      d *= e;
    }
  }
  o[(size_t)row * 1024 + col] = __float2bfloat16(acc);
}

extern "C" void kernel_launch(void* const* d_in, const int* in_sizes, int n_in,
                              void* d_out, int out_size, void* d_ws, size_t ws_size,
                              hipStream_t stream) {
  const float* X  = (const float*)d_in[0];
  const float* Wq = (const float*)d_in[1];
  const float* Wf = (const float*)d_in[2];
  const float* Wi = (const float*)d_in[3];
  const float* Wo = (const float*)d_in[4];
  float* out = (float*)d_out;

  __hip_bfloat16* qfv = (__hip_bfloat16*)d_ws;       // [8192][3072] bf16, 48 MiB
  __hip_bfloat16* Xb  = qfv + (size_t)8192 * 3072;   // 16 MiB
  __hip_bfloat16* Wall = Xb + NE;                    // [4][1024][1024] bf16, 8 MiB
  __hip_bfloat16* ob  = Xb;  // alias: Xb dead after QFV GEMM

  cvt_bf16<<<NE / 4 / 256, 256, 0, stream>>>(X, Xb);
  cvt_transpose4<<<dim3(32, 32, 4), 256, 0, stream>>>(Wq, Wf, Wi, Wo, Wall);

  gemm_pipe<1><<<dim3(24, 32), 512, 0, stream>>>(Xb, Wall, nullptr, qfv, 1024);
  rowsoft2<<<16384, 256, 0, stream>>>(qfv);
  gla_recur<<<32768, 256, 0, stream>>>(qfv, ob);
  gemm_pipe<0><<<dim3(8, 32), 512, 0, stream>>>(ob, Wall + (size_t)3 * 1024 * 1024,
                                                out, nullptr, 1024);
}